// Round 11
// baseline (228.796 us; speedup 1.0000x reference)
//
#include <hip/hip_runtime.h>
#include <hip/hip_bf16.h>

// ---------------------------------------------------------------------------
// EnsembleTransitionMLP: fused 4-layer MLP over 50 ensembles, bf16 MFMA.
// Round 16 (R15 + OOB guard fix):
//  - R15 FAILED (absmax 0.365): the templated unroll dropped the `u < NT*64`
//    guard in the repack stage. W4 has NT*64 = 192 < 256 -> threads 192-255
//    wrote out-of-bounds uint4s (nt=3 >= NT), corrupting w4P/biasP. Guard
//    restored; W1/W2/W3 (1024, multiple of 256) were never affected.
//  - cvt_pk pack_bf2 + compile-time-unrolled k_pack KEPT (R15's intent):
//    1 VALU per 2 floats packing; panel loads issue under one vmcnt drain.
//  - k_mlp structure VERBATIM R13/R14 ((256,4), XCD swizzle, T5 setprio).
// Fragment layouts (16x16x32 bf16, same as R2-R14):
//   A: lane l holds A[m=l&15][k=(l>>4)*8+j]   (weights as W^T)
//   B: lane l holds B[k=(l>>4)*8+j][n=l&15]   (h^T: k=feat, n=batch)
//   C/D: lane l, reg r: feat=(l>>4)*4+r, batch=l&15
// ---------------------------------------------------------------------------

typedef __attribute__((ext_vector_type(8))) short short8;
typedef __attribute__((ext_vector_type(4))) float floatx4;

#define NE 50
#define NB 8192
#define OUT_NS_ELEMS (NB * NE * 32)
#define OSTRIDE 48  // shorts; 96B = 16B-aligned rows for b128 reads

__device__ __forceinline__ unsigned short f2bf_rne(float x) {
  unsigned u = __float_as_uint(x);
  u += 0x7fffu + ((u >> 16) & 1u);
  return (unsigned short)(u >> 16);
}
__device__ __forceinline__ float bf2f(unsigned short b) {
  return __uint_as_float(((unsigned)b) << 16);
}
__device__ __forceinline__ floatx4 mfma16(short8 a, short8 b, floatx4 c) {
  return __builtin_amdgcn_mfma_f32_16x16x32_bf16(a, b, c, 0, 0, 0);
}
// pack two f32 -> one dword of bf16 pair via v_cvt_pk_bf16_f32 (RNE)
__device__ __forceinline__ unsigned pack_bf2(float lo, float hi) {
  union { __hip_bfloat162 h2; unsigned u; } c;
  c.h2 = __float22bfloat162_rn(make_float2(lo, hi));
  return c.u;
}

__device__ __forceinline__ unsigned short load_bf(const void* p, long i, bool isbf) {
  if (isbf) return ((const unsigned short*)p)[i];
  return f2bf_rne(((const float*)p)[i]);
}
__device__ __forceinline__ float load_f(const void* p, long i, bool isbf) {
  if (isbf) return bf2f(((const unsigned short*)p)[i]);
  return ((const float*)p)[i];
}

// ---------------- mega pack (32-row panels; compile-time unrolled) ---------
// W pack layout per ensemble (B-fragment order):
//   elt = (((kt*NT + nt)*4 + kb)*16 + ni)*8 + j ; k = kt*32+kb*8+j ; n = nt*16+ni
template <int K, int N, int NT, int PERE>
__device__ __forceinline__ void pack_w_panel(const void* __restrict__ src,
                                             unsigned short* __restrict__ dst,
                                             bool isbf, int e, int kt,
                                             unsigned short* lds) {
  const int t = threadIdx.x;
  constexpr int Npad = NT * 16;
  constexpr int NP = Npad + 10;
  if constexpr (N == Npad) {
    if (!isbf) {
      // f32 full-width rows: float4 loads + cvt_pk packing
      constexpr int nq = Npad >> 2;
#pragma unroll
      for (int idx0 = 0; idx0 < 32 * nq; idx0 += 256) {
        int idx = idx0 + t;
        int r = idx / nq, q = idx - r * nq;
        int k = kt * 32 + r;
        unsigned w0 = 0, w1 = 0;
        if (k < K) {
          const float4 f =
              *(const float4*)((const float*)src + ((long)(e * K + k) * N + q * 4));
          w0 = pack_bf2(f.x, f.y);
          w1 = pack_bf2(f.z, f.w);
        }
        unsigned* p = (unsigned*)(lds + r * NP + q * 4);
        p[0] = w0;
        p[1] = w1;
      }
    } else {
      // bf16 full-width rows: uint4 loads
      constexpr int no = Npad >> 3;
#pragma unroll
      for (int idx0 = 0; idx0 < 32 * no; idx0 += 256) {
        int idx = idx0 + t;
        int r = idx / no, q = idx - r * no;
        int k = kt * 32 + r;
        uint4 f = make_uint4(0u, 0u, 0u, 0u);
        if (k < K)
          f = *(const uint4*)((const unsigned short*)src +
                              ((long)(e * K + k) * N + q * 8));
        unsigned* p = (unsigned*)(lds + r * NP + q * 8);
        p[0] = f.x; p[1] = f.y; p[2] = f.z; p[3] = f.w;
      }
    }
  } else {
    // scalar fallback (W4: N=33 ragged rows); 32*Npad = 1536 (mult of 256)
#pragma unroll
    for (int idx0 = 0; idx0 < 32 * Npad; idx0 += 256) {
      int idx = idx0 + t;
      int r = idx / Npad, c = idx - r * Npad;
      int k = kt * 32 + r;
      unsigned short v = 0;
      if (k < K && c < N) v = load_bf(src, (long)(e * K + k) * N + c, isbf);
      lds[r * NP + c] = v;
    }
  }
  __syncthreads();
  // repack: NT*64 may be < 256 (W4: 192) -> GUARD IS REQUIRED (R15 bug).
#pragma unroll
  for (int u0 = 0; u0 < NT * 64; u0 += 256) {
    int u = u0 + t;
    if (u < NT * 64) {
      int nt = u >> 6, kb = (u >> 4) & 3, ni = u & 15;
      int n = nt * 16 + ni;
      unsigned v[4];
#pragma unroll
      for (int p = 0; p < 4; ++p) {
        unsigned lo = lds[(kb * 8 + 2 * p) * NP + n];
        unsigned hi = lds[(kb * 8 + 2 * p + 1) * NP + n];
        v[p] = lo | (hi << 16);
      }
      long off = (long)e * PERE + ((long)((kt * NT + nt) * 64 + kb * 16 + ni)) * 8;
      *(uint4*)(dst + off) = make_uint4(v[0], v[1], v[2], v[3]);
    }
  }
}

__global__ void k_pack(const void* __restrict__ state, const void* __restrict__ action,
                       const void* __restrict__ W1, const void* __restrict__ W2,
                       const void* __restrict__ W3, const void* __restrict__ W4,
                       const void* __restrict__ b1, const void* __restrict__ b2,
                       const void* __restrict__ b3, const void* __restrict__ b4,
                       int isbfi,
                       unsigned short* __restrict__ saP, unsigned short* __restrict__ w1P,
                       unsigned short* __restrict__ w2P, unsigned short* __restrict__ w3P,
                       unsigned short* __restrict__ w4P, float* __restrict__ biasP) {
  __shared__ unsigned short lds[32 * 266];  // 17,024 B
  const bool isbf = (isbfi != 0);
  const int b = blockIdx.x;
  if (b < 400) {
    pack_w_panel<256, 256, 16, 65536>(W2, w2P, isbf, b >> 3, b & 7, lds);
  } else if (b < 800) {
    int bb = b - 400;
    pack_w_panel<256, 256, 16, 65536>(W3, w3P, isbf, bb >> 3, bb & 7, lds);
  } else if (b < 900) {
    int bb = b - 800;
    pack_w_panel<40, 256, 16, 16384>(W1, w1P, isbf, bb >> 1, bb & 1, lds);
  } else if (b < 1300) {
    int bb = b - 900;
    pack_w_panel<256, 33, 3, 12288>(W4, w4P, isbf, bb >> 3, bb & 7, lds);
  } else if (b < 1364) {
    // sa pack, vectorized: unit-lane u needs 8 CONSECUTIVE k of one row.
    //   u: mi=u&15, kb=(u>>4)&7, mt=u>>7; row=mt*16+mi; k = kb*8..kb*8+7
    //   (K padded 40->64: kb<4 state, kb==4 action, else zero)
    int bb = b - 1300;
#pragma unroll
    for (int c = 0; c < 4; ++c) {
      int u = bb * 1024 + c * 256 + threadIdx.x;  // lanes consecutive -> coalesced
      int mi = u & 15, kb = (u >> 4) & 7, mt = u >> 7;
      int row = mt * 16 + mi;
      uint4 v = make_uint4(0u, 0u, 0u, 0u);
      if (isbf) {
        if (kb < 4)
          v = *(const uint4*)((const unsigned short*)state + (long)row * 32 + kb * 8);
        else if (kb == 4)
          v = *(const uint4*)((const unsigned short*)action + (long)row * 8);
      } else {
        if (kb < 4) {
          const float* sp = (const float*)state + (long)row * 32 + kb * 8;
          const float4 f0 = *(const float4*)(sp);
          const float4 f1 = *(const float4*)(sp + 4);
          v.x = pack_bf2(f0.x, f0.y);
          v.y = pack_bf2(f0.z, f0.w);
          v.z = pack_bf2(f1.x, f1.y);
          v.w = pack_bf2(f1.z, f1.w);
        } else if (kb == 4) {
          const float* ap = (const float*)action + (long)row * 8;
          const float4 f0 = *(const float4*)(ap);
          const float4 f1 = *(const float4*)(ap + 4);
          v.x = pack_bf2(f0.x, f0.y);
          v.y = pack_bf2(f0.z, f0.w);
          v.z = pack_bf2(f1.x, f1.y);
          v.w = pack_bf2(f1.z, f1.w);
        }
      }
      *(uint4*)(saP + (long)u * 8) = v;
    }
  } else {
    // bias: per e: [b1(256)][b2(256)][b3(256)][b4(48 zero-padded)]
    int gid = (b - 1364) * 256 + threadIdx.x;
    if (gid < NE * 816) {
      int e = gid / 816, r = gid - e * 816;
      float v = 0.0f;
      if (r < 256)      v = load_f(b1, e * 256 + r,         isbf);
      else if (r < 512) v = load_f(b2, e * 256 + (r - 256), isbf);
      else if (r < 768) v = load_f(b3, e * 256 + (r - 512), isbf);
      else { int q = r - 768; if (q < 33) v = load_f(b4, e * 33 + q, isbf); }
      biasP[gid] = v;
    }
  }
}

// ---------------- fused MLP (R13 structure + cvt_pk epilogue) --------------
// hT in LDS (32KB), B-frag units for BM=64:
//   short addr(k,b) = ((k>>5)*4 + (b>>4))*512 + ((k>>3)&3)*128 + (b&15)*8 + (k&7)
// B-frag read (kt, bt): 16B at ((kt*4 + bt)*64 + l)*8.

__device__ __forceinline__ void store_tile16(const floatx4& a4, unsigned short* hT,
                                             int FT, int BT, int li, int g) {
  int k0 = FT * 16 + g * 4;
  unsigned d0 = pack_bf2(fmaxf(a4[0], 0.0f), fmaxf(a4[1], 0.0f));
  unsigned d1 = pack_bf2(fmaxf(a4[2], 0.0f), fmaxf(a4[3], 0.0f));
  int addr = ((k0 >> 5) * 4 + BT) * 512 + ((k0 >> 3) & 3) * 128 + li * 8 + (k0 & 7);
  *(unsigned long long*)(hT + addr) =
      (unsigned long long)d0 | ((unsigned long long)d1 << 32);
}

// wave wf owns feats [wf*64, wf*64+64) x all 64 batch: acc[4 ftiles][4 btiles]
__device__ __forceinline__ void hidden_layer(const unsigned short* __restrict__ wp,
                                             const float* __restrict__ br,
                                             unsigned short* hT,
                                             int wf, int l, int li, int g) {
  floatx4 acc[4][4];
#pragma unroll
  for (int ot = 0; ot < 4; ++ot) {
    const float4 bq = *(const float4*)(br + wf * 64 + ot * 16 + g * 4);
    floatx4 iv = {bq.x, bq.y, bq.z, bq.w};
#pragma unroll
    for (int bt = 0; bt < 4; ++bt) acc[ot][bt] = iv;
  }
#pragma unroll
  for (int kt = 0; kt < 8; ++kt) {
    short8 a[4];
#pragma unroll
    for (int ot = 0; ot < 4; ++ot)
      a[ot] = *(const short8*)(wp + (long)((kt * 16 + wf * 4 + ot) * 64 + l) * 8);
    __builtin_amdgcn_s_setprio(1);
#pragma unroll
    for (int bt = 0; bt < 4; ++bt) {
      short8 b = *(const short8*)(hT + ((kt * 4 + bt) * 64 + l) * 8);
#pragma unroll
      for (int ot = 0; ot < 4; ++ot)
        acc[ot][bt] = mfma16(a[ot], b, acc[ot][bt]);
    }
    __builtin_amdgcn_s_setprio(0);
  }
  __syncthreads();  // all reads of hT done before in-place overwrite
#pragma unroll
  for (int ot = 0; ot < 4; ++ot)
#pragma unroll
    for (int bt = 0; bt < 4; ++bt)
      store_tile16(acc[ot][bt], hT, wf * 4 + ot, bt, li, g);
  __syncthreads();
}

__global__ __launch_bounds__(256, 4) void k_mlp(
    const unsigned short* __restrict__ sa,
    const unsigned short* __restrict__ w1,
    const unsigned short* __restrict__ w2,
    const unsigned short* __restrict__ w3,
    const unsigned short* __restrict__ w4,
    const float* __restrict__ bias,
    int isbfi,
    float* __restrict__ rewardWS,
    void* __restrict__ outp) {
  __shared__ __attribute__((aligned(16))) unsigned short hT[16384];  // 32 KB
  const int tid = threadIdx.x;
  const int wf = tid >> 6, l = tid & 63, li = l & 15, g = l >> 4;

  // XCD-aware swizzle (bijective, 6400%8==0). R8: FETCH 66->15.9MB confirmed.
  const int lid = blockIdx.y * 128 + blockIdx.x;
  const int swz = (lid & 7) * 800 + (lid >> 3);
  const int e  = swz >> 7;         // ensemble
  const int bb = swz & 127;        // 64-row batch tile (128 tiles)

  const float* brow = bias + e * 816;
  const bool isbf = (isbfi != 0);

  // ---- layer 1: W1^T(256x64) * sa^T(64x64) -> h1^T in LDS ----
  {
    floatx4 acc[4][4];
#pragma unroll
    for (int ot = 0; ot < 4; ++ot) {
      const float4 bq = *(const float4*)(brow + wf * 64 + ot * 16 + g * 4);
      floatx4 iv = {bq.x, bq.y, bq.z, bq.w};
#pragma unroll
      for (int bt = 0; bt < 4; ++bt) acc[ot][bt] = iv;
    }
#pragma unroll
    for (int kt = 0; kt < 2; ++kt) {
      short8 a[4];
#pragma unroll
      for (int ot = 0; ot < 4; ++ot)
        a[ot] = *(const short8*)(w1 + (long)e * 16384 +
                                 (long)((kt * 16 + wf * 4 + ot) * 64 + l) * 8);
      __builtin_amdgcn_s_setprio(1);
#pragma unroll
      for (int bt = 0; bt < 4; ++bt) {
        short8 b = *(const short8*)(sa + (long)((bb * 4 + bt) * 128 + kt * 64 + l) * 8);
#pragma unroll
        for (int ot = 0; ot < 4; ++ot)
          acc[ot][bt] = mfma16(a[ot], b, acc[ot][bt]);
      }
      __builtin_amdgcn_s_setprio(0);
    }
#pragma unroll
    for (int ot = 0; ot < 4; ++ot)
#pragma unroll
      for (int bt = 0; bt < 4; ++bt)
        store_tile16(acc[ot][bt], hT, wf * 4 + ot, bt, li, g);
    __syncthreads();
  }

  // ---- layers 2, 3 ----
  hidden_layer(w2 + (long)e * 65536, brow + 256, hT, wf, l, li, g);
  hidden_layer(w3 + (long)e * 65536, brow + 512, hT, wf, l, li, g);

  // ---- layer 4: W4^T(48x256) * h3^T(256x64); wave wf owns btile wf ----
  const float* brow4 = brow + 768;
  floatx4 acc4[3];
#pragma unroll
  for (int ft = 0; ft < 3; ++ft) {
    const float4 bq = *(const float4*)(brow4 + ft * 16 + g * 4);
    floatx4 iv = {bq.x, bq.y, bq.z, bq.w};
    acc4[ft] = iv;
  }
#pragma unroll
  for (int kt = 0; kt < 8; ++kt) {
    short8 a[3];
#pragma unroll
    for (int ft = 0; ft < 3; ++ft)
      a[ft] = *(const short8*)(w4 + (long)e * 12288 + (long)((kt * 3 + ft) * 64 + l) * 8);
    short8 b = *(const short8*)(hT + ((kt * 4 + wf) * 64 + l) * 8);
    __builtin_amdgcn_s_setprio(1);
#pragma unroll
    for (int ft = 0; ft < 3; ++ft)
      acc4[ft] = mfma16(a[ft], b, acc4[ft]);
    __builtin_amdgcn_s_setprio(0);
  }

  // reward (feat 32 = ft2, g==0, reg 0) -> staged coalesced into ws[e][batch]
  if (g == 0) {
    rewardWS[(long)e * NB + bb * 64 + wf * 16 + li] = acc4[2][0];
  }

  __syncthreads();  // all hT reads done; reuse hT as output staging buffer
  // stage out^T tiles -> osta[batch][feat] (bf16, stride OSTRIDE)
#pragma unroll
  for (int ft = 0; ft < 2; ++ft) {
    int batch = wf * 16 + li;
    unsigned d0 = pack_bf2(acc4[ft][0], acc4[ft][1]);
    unsigned d1 = pack_bf2(acc4[ft][2], acc4[ft][3]);
    *(unsigned long long*)(hT + batch * OSTRIDE + ft * 16 + g * 4) =
        (unsigned long long)d0 | ((unsigned long long)d1 << 32);
  }
  __syncthreads();

  // coalesced store: full 64B line per (batch,e)
  if (isbf) {
    unsigned short* o16 = (unsigned short*)outp;
    int batch = tid >> 2;
    int chunk = tid & 3;  // 8 shorts each
    uint4 v = *(const uint4*)(hT + batch * OSTRIDE + chunk * 8);
    *(uint4*)(o16 + ((long)(bb * 64 + batch) * NE + e) * 32 + chunk * 8) = v;
  } else {
    float* o32 = (float*)outp;
#pragma unroll
    for (int p = 0; p < 2; ++p) {
      int idx = p * 256 + tid;
      int batch = idx >> 3;
      int chunk = idx & 7;  // 4 floats each
      const unsigned short* s = hT + batch * OSTRIDE + chunk * 4;
      *(float4*)(o32 + ((long)(bb * 64 + batch) * NE + e) * 32 + chunk * 4) =
          make_float4(bf2f(s[0]), bf2f(s[1]), bf2f(s[2]), bf2f(s[3]));
    }
  }
}

// ---------------- reward transpose epilogue (LDS transpose) ----------------
// 64 blocks; block g: b in [g*128, g*128+128), all e in [0,50).
__global__ void k_reward(const float* __restrict__ rw, int isbfi,
                         void* __restrict__ outp) {
  __shared__ float lt[128 * 51];  // 26,112 B (51 stride: bank-spread)
  const int t = threadIdx.x;
  const int g = blockIdx.x;
  for (int i = 0; i < 25; ++i) {
    int idx = i * 256 + t;  // < 6400
    int e = idx >> 7, bo = idx & 127;
    lt[bo * 51 + e] = rw[(long)e * NB + g * 128 + bo];
  }
  __syncthreads();
  if (isbfi != 0) {
    unsigned short* o16 = (unsigned short*)outp + OUT_NS_ELEMS + g * 6400;
    for (int i = 0; i < 25; ++i) {
      int j = i * 256 + t;  // < 6400
      int bo = j / 50, e = j - bo * 50;
      o16[j] = f2bf_rne(lt[bo * 51 + e]);
    }
  } else {
    float* o32 = (float*)outp + OUT_NS_ELEMS + g * 6400;
    for (int i = 0; i < 25; ++i) {
      int j = i * 256 + t;  // < 6400
      int bo = j / 50, e = j - bo * 50;
      o32[j] = lt[bo * 51 + e];
    }
  }
}

// ---------------------------------------------------------------------------
extern "C" void kernel_launch(void* const* d_in, const int* in_sizes, int n_in,
                              void* d_out, int out_size, void* d_ws, size_t ws_size,
                              hipStream_t stream) {
  const void* state  = d_in[0];
  const void* action = d_in[1];
  const void* W1 = d_in[2];
  const void* b1 = d_in[3];
  const void* W2 = d_in[4];
  const void* b2 = d_in[5];
  const void* W3 = d_in[6];
  const void* b3 = d_in[7];
  const void* W4 = d_in[8];
  const void* b4 = d_in[9];
  (void)n_in; (void)out_size; (void)ws_size;

  // dtype from buffer size: W2 = 50*256*256 elems; bf16 -> 6,553,600 B.
  const int isbf = (in_sizes[4] == NE * 256 * 256 * 2) ? 1 : 0;

  char* ws = (char*)d_ws;
  unsigned short* saP    = (unsigned short*)(ws + 256);        // 1,048,576 B
  unsigned short* w1P    = (unsigned short*)(ws + 1048832);    // 1,638,400 B
  unsigned short* w2P    = (unsigned short*)(ws + 2687232);    // 6,553,600 B
  unsigned short* w3P    = (unsigned short*)(ws + 9240832);    // 6,553,600 B
  unsigned short* w4P    = (unsigned short*)(ws + 15794432);   // 1,228,800 B
  float* biasP           = (float*)(ws + 17023232);            //   163,200 B
  float* rewardWS        = (float*)(ws + 17186432);            // 1,638,400 B
  // total ws use: 18,824,832 B

  // grid: W2 400 | W3 400 | W1 100 | W4 400 | sa 64 | bias 160 = 1524
  k_pack<<<1524, 256, 0, stream>>>(state, action, W1, W2, W3, W4, b1, b2, b3, b4,
                                   isbf, saP, w1P, w2P, w3P, w4P, biasP);
  k_mlp<<<dim3(128, 50), 256, 0, stream>>>(saP, w1P, w2P, w3P, w4P, biasP, isbf,
                                           rewardWS, d_out);
  k_reward<<<64, 256, 0, stream>>>(rewardWS, isbf, d_out);
}